// Round 2
// baseline (167.221 us; speedup 1.0000x reference)
//
#include <hip/hip_runtime.h>
#include <hip/hip_bf16.h>

// Attention B=4,N=2048,D=384,H=8,DH=48 — Round 16:
//  - attn REWRITE: barrier-free K-loop. K/V fragments loaded global->VGPR
//    directly (L1 dedups identical addresses across the 4 waves); rolling
//    1-tile register prefetch; l via in-register f32 sum + shfl_xor(32).
//    No LDS in the loop (epilogue transpose only). No K-split, no comb.
//  - qkv: V-epilogue applies the kappa bit2<->bit3 token permutation so
//    attn PV A-frags are single contiguous f16x8 loads.
//  - prep/proj unchanged.

typedef _Float16 f16x8 __attribute__((ext_vector_type(8)));
typedef _Float16 f16x4 __attribute__((ext_vector_type(4)));
typedef float    f32x4 __attribute__((ext_vector_type(4)));
typedef float    f32x16 __attribute__((ext_vector_type(16)));

// scale * log2(e) = 48^-0.5 * 1.4426950408889634
#define QSCL 0.20822035963448658f

// ---------------------------------------------------------------------------
// prep: blocks 0..143 transpose weights (LDS-tiled); 144..399 convert x->f16
// ---------------------------------------------------------------------------
__global__ __launch_bounds__(256) void prep(const float4* __restrict__ x,
                                            const float* __restrict__ wq,
                                            const float* __restrict__ wp,
                                            f16x4* __restrict__ xh4,
                                            _Float16* __restrict__ wqt,
                                            _Float16* __restrict__ wpt)
{
    __shared__ _Float16 t[64][65];
    const int blk = blockIdx.x, tid = threadIdx.x;
    if (blk < 144) {
        const float* src; _Float16* dst; int Nn, k0, n0;
        if (blk < 108) {            // Wqkv: 6 k-tiles x 18 n-tiles
            src = wq; dst = wqt; Nn = 1152;
            k0 = (blk % 6) * 64; n0 = (blk / 6) * 64;
        } else {                    // Wproj: 6 x 6
            const int b2 = blk - 108;
            src = wp; dst = wpt; Nn = 384;
            k0 = (b2 % 6) * 64; n0 = (b2 / 6) * 64;
        }
        #pragma unroll
        for (int i = 0; i < 16; i++) {
            const int id = tid + i * 256;
            const int k = id >> 6, n = id & 63;      // coalesced over n
            t[k][n] = (_Float16)src[(size_t)(k0 + k) * Nn + n0 + n];
        }
        __syncthreads();
        #pragma unroll
        for (int i = 0; i < 16; i++) {
            const int id = tid + i * 256;
            const int n = id >> 6, k = id & 63;      // coalesced over k
            dst[(size_t)(n0 + n) * 384 + k0 + k] = t[k][n];
        }
    } else {
        const int base = (blk - 144) * 3072;         // 256 blocks x 3072 = 786432
        #pragma unroll
        for (int r = 0; r < 12; r++) {
            const int j = base + r * 256 + tid;
            const float4 tt = x[j];
            f16x4 hh;
            hh[0] = (_Float16)tt.x; hh[1] = (_Float16)tt.y;
            hh[2] = (_Float16)tt.z; hh[3] = (_Float16)tt.w;
            xh4[j] = hh;
        }
    }
}

// ---------------------------------------------------------------------------
// QKV GEMM: A = xh[8192][384] f16, Bt = wqkvt[1152][384] f16.
// 128x128 tile, BK=32, padded LDS (stride 40), 16x16x32 MFMA, 4 waves,
// reg-prefetch. Epilogue via LDS transpose -> coalesced f16x8 stores.
// V epilogue stores the kappa-permuted token order (bits 2<->3 of token%16)
// so attn's PV A-fragments are contiguous f16x8 loads.
// ---------------------------------------------------------------------------
union QkvSmem {
    struct { _Float16 As[128][40]; _Float16 Bs[128][40]; } g;  // 20480 B
    _Float16 Ts[128][136];   // V transpose   [col][n]   34816 B
    _Float16 Ts2[128][136];  // q/k transpose [row][col] 34816 B
};

__global__ __launch_bounds__(256) void qkv_f16(const _Float16* __restrict__ A,
                                               const _Float16* __restrict__ Bt,
                                               _Float16* __restrict__ qh,
                                               _Float16* __restrict__ kh,
                                               _Float16* __restrict__ vt)
{
    __shared__ QkvSmem sm;
    const int tid = threadIdx.x;
    const int w = tid >> 6, lane = tid & 63, cl = lane & 15, quad = lane >> 4;
    const int bm = blockIdx.x, bn = blockIdx.y;

    f32x4 acc[2][8];
    const f32x4 z4 = {0.f, 0.f, 0.f, 0.f};
    #pragma unroll
    for (int mi = 0; mi < 2; mi++)
        #pragma unroll
        for (int t = 0; t < 8; t++) acc[mi][t] = z4;

    const int ar = tid >> 2, ac = (tid & 3) * 8;     // 512 chunks: 2/thread
    const _Float16* Ag = A  + (size_t)(bm * 128 + ar) * 384 + ac;
    const _Float16* Bg = Bt + (size_t)(bn * 128 + ar) * 384 + ac;

    f16x8 pa[2], pb[2];
    #pragma unroll
    for (int j = 0; j < 2; j++) {
        pa[j] = *(const f16x8*)(Ag + (size_t)(64 * j) * 384);
        pb[j] = *(const f16x8*)(Bg + (size_t)(64 * j) * 384);
    }

    for (int k0 = 0; k0 < 384; k0 += 32) {
        __syncthreads();
        #pragma unroll
        for (int j = 0; j < 2; j++) {
            *(f16x8*)&sm.g.As[ar + 64 * j][ac] = pa[j];
            *(f16x8*)&sm.g.Bs[ar + 64 * j][ac] = pb[j];
        }
        __syncthreads();
        if (k0 + 32 < 384) {
            #pragma unroll
            for (int j = 0; j < 2; j++) {
                pa[j] = *(const f16x8*)(Ag + (size_t)(64 * j) * 384 + k0 + 32);
                pb[j] = *(const f16x8*)(Bg + (size_t)(64 * j) * 384 + k0 + 32);
            }
        }
        f16x8 bf[8];
        #pragma unroll
        for (int t = 0; t < 8; t++)
            bf[t] = *(const f16x8*)&sm.g.Bs[t * 16 + cl][quad * 8];
        #pragma unroll
        for (int mi = 0; mi < 2; mi++) {
            const f16x8 af = *(const f16x8*)&sm.g.As[w * 32 + mi * 16 + cl][quad * 8];
            #pragma unroll
            for (int t = 0; t < 8; t++)
                acc[mi][t] = __builtin_amdgcn_mfma_f32_16x16x32_f16(af, bf[t], acc[mi][t], 0, 0, 0);
        }
    }

    const int s = (bn * 128) / 384;    // uniform per block (384 % 128 == 0)
    const int b  = (bm * 128) >> 11;
    const int n0 = (bm * 128) & 2047;
    if (s == 2) {
        // ---- V: LDS transpose [col][token'] with kappa perm on token%16 ----
        __syncthreads();
        const int qp = ((quad & 1) << 1) | (quad >> 1);   // swap bits of quad
        #pragma unroll
        for (int t = 0; t < 8; t++)
            #pragma unroll
            for (int mi = 0; mi < 2; mi++)
                #pragma unroll
                for (int r = 0; r < 4; r++)
                    sm.Ts[t * 16 + cl][w * 32 + mi * 16 + qp * 4 + r] =
                        (_Float16)acc[mi][t][r];
        __syncthreads();
        const int colbase = bn * 128 - 768;      // 0,128,256
        #pragma unroll
        for (int i = 0; i < 8; i++) {
            const int c = i * 256 + tid;         // 0..2047 chunks of 8
            const int col = c >> 4, nc = c & 15;
            const int gcol = colbase + col;
            const int head = gcol / 48, d = gcol - head * 48;
            const int bh = b * 8 + head;
            *(f16x8*)&vt[(size_t)(bh * 48 + d) * 2048 + n0 + nc * 8] =
                *(const f16x8*)&sm.Ts[col][nc * 8];
        }
    } else {
        // ---- q/k: LDS transpose [row][col] -> coalesced f16x8 stores ----
        __syncthreads();
        const float scl = (s == 0) ? QSCL : 1.0f;
        #pragma unroll
        for (int t = 0; t < 8; t++)
            #pragma unroll
            for (int mi = 0; mi < 2; mi++)
                #pragma unroll
                for (int r = 0; r < 4; r++)
                    sm.Ts2[w * 32 + mi * 16 + quad * 4 + r][t * 16 + cl] =
                        (_Float16)(acc[mi][t][r] * scl);
        __syncthreads();
        _Float16* dst = (s == 0) ? qh : kh;
        const int colbase = bn * 128 - s * 384;  // 0,128,256
        #pragma unroll
        for (int i = 0; i < 8; i++) {
            const int c = i * 256 + tid;         // 0..2047 chunks of 8
            const int row = c >> 4, ch = c & 15;
            const int gcol = colbase + ch * 8;   // multiple of 8; 48=6x8 -> no straddle
            const int head = gcol / 48, d = gcol - head * 48;
            const int bh = b * 8 + head;
            *(f16x8*)&dst[(size_t)(bh * 2048 + n0 + row) * 48 + d] =
                *(const f16x8*)&sm.Ts2[row][ch * 8];
        }
    }
}

// ---------------------------------------------------------------------------
// Flash attention (R16): barrier-free. Each wave owns 32 queries; K/V frags
// loaded straight from global (L1 broadcasts identical addresses across the
// block's 4 waves). Rolling 1-tile register prefetch. 32x32x16 f16 MFMA,
// no-max softmax, l = f32 register sum + shfl_xor(32). Epilogue LDS only.
// ---------------------------------------------------------------------------
__global__ __launch_bounds__(256) void attn_f16(const _Float16* __restrict__ qh,
                                                const _Float16* __restrict__ kh,
                                                const _Float16* __restrict__ vt,
                                                _Float16* __restrict__ ab)
{
    __shared__ _Float16 Ot[128][58];   // epilogue transpose [q][dh] 14848 B
    const int tid = threadIdx.x;
    const int w = tid >> 6, lane = tid & 63, ln = lane & 31, h = lane >> 5;
    const int bh = blockIdx.x, qt = blockIdx.y;

    // Q B-frags (3, dh = 16i + 8h + 0..7), query = qt*128 + w*32 + ln
    f16x8 qf[3];
    {
        const _Float16* qp = qh + (size_t)(bh * 2048 + qt * 128 + w * 32 + ln) * 48 + 8 * h;
        qf[0] = *(const f16x8*)qp;
        qf[1] = *(const f16x8*)(qp + 16);
        qf[2] = *(const f16x8*)(qp + 32);
    }

    f32x16 o0, o1;
    #pragma unroll
    for (int r = 0; r < 16; r++) { o0[r] = 0.f; o1[r] = 0.f; }
    float lsum = 0.f;

    // K rows ln and ln+32 (always in-head); V rows ln and 32+ln (rows 48..63
    // bleed into the next head's data -> only feed DISCARDED o1 accumulators;
    // clamp so the last head stays inside the vt buffer).
    const _Float16* kp  = kh + ((size_t)bh * 2048 + ln) * 48 + 8 * h;
    const int vrow1 = min(bh * 48 + 32 + ln, 32 * 48 - 1);
    const _Float16* vp0 = vt + ((size_t)bh * 48 + ln) * 2048 + 8 * h;
    const _Float16* vp1 = vt + (size_t)vrow1 * 2048 + 8 * h;

    // prefetch tile 0
    f16x8 kf[6], vf[8];
    #pragma unroll
    for (int i = 0; i < 3; i++) {
        kf[i]     = *(const f16x8*)(kp + 16 * i);
        kf[3 + i] = *(const f16x8*)(kp + (size_t)32 * 48 + 16 * i);
    }
    #pragma unroll
    for (int c = 0; c < 4; c++) {
        vf[c]     = *(const f16x8*)(vp0 + 16 * c);
        vf[4 + c] = *(const f16x8*)(vp1 + 16 * c);
    }

    for (int t = 0; t < 32; ++t) {
        const int nxt = ((t + 1) & 31) * 64;   // wraps to 0 on last iter (dummy)

        // ---- S^T = K.Q^T : C[key][query] ----
        f32x16 s0, s1;
        #pragma unroll
        for (int r = 0; r < 16; r++) { s0[r] = 0.f; s1[r] = 0.f; }
        __builtin_amdgcn_s_setprio(1);
        #pragma unroll
        for (int i = 0; i < 3; i++) {
            s0 = __builtin_amdgcn_mfma_f32_32x32x16_f16(kf[i],     qf[i], s0, 0, 0, 0);
            s1 = __builtin_amdgcn_mfma_f32_32x32x16_f16(kf[3 + i], qf[i], s1, 0, 0, 0);
        }
        __builtin_amdgcn_s_setprio(0);

        // ---- prefetch next K tile (in flight across exp+PV) ----
        #pragma unroll
        for (int i = 0; i < 3; i++) {
            kf[i]     = *(const f16x8*)(kp + (size_t)nxt * 48 + 16 * i);
            kf[3 + i] = *(const f16x8*)(kp + (size_t)(nxt + 32) * 48 + 16 * i);
        }

        // ---- P = exp2(S^T) packed as PV B-frags; l accumulated in f32 ----
        f16x8 pbf[4];
        float ls0 = 0.f, ls1 = 0.f, ls2 = 0.f, ls3 = 0.f;
        #pragma unroll
        for (int j = 0; j < 8; j++) {
            const float e0 = __builtin_amdgcn_exp2f(s0[j]);
            const float e1 = __builtin_amdgcn_exp2f(s0[8 + j]);
            const float e2 = __builtin_amdgcn_exp2f(s1[j]);
            const float e3 = __builtin_amdgcn_exp2f(s1[8 + j]);
            ls0 += e0; ls1 += e1; ls2 += e2; ls3 += e3;
            pbf[0][j] = (_Float16)e0;
            pbf[1][j] = (_Float16)e1;
            pbf[2][j] = (_Float16)e2;
            pbf[3][j] = (_Float16)e3;
        }
        lsum += (ls0 + ls1) + (ls2 + ls3);

        // ---- O^T += V^T.P^T ----
        __builtin_amdgcn_s_setprio(1);
        #pragma unroll
        for (int c = 0; c < 4; c++) {
            o0 = __builtin_amdgcn_mfma_f32_32x32x16_f16(vf[c],     pbf[c], o0, 0, 0, 0);
            o1 = __builtin_amdgcn_mfma_f32_32x32x16_f16(vf[4 + c], pbf[c], o1, 0, 0, 0);
        }
        __builtin_amdgcn_s_setprio(0);

        // ---- prefetch next V tile ----
        #pragma unroll
        for (int c = 0; c < 4; c++) {
            vf[c]     = *(const f16x8*)(vp0 + nxt + 16 * c);
            vf[4 + c] = *(const f16x8*)(vp1 + nxt + 16 * c);
        }
    }

    // ---- l(q=ln) = own-half sum + other-half sum ----
    const float inv = 1.f / (lsum + __shfl_xor(lsum, 32));

    // ---- epilogue: O^T -> LDS transpose -> coalesced stores ----
    #pragma unroll
    for (int r = 0; r < 16; r++)
        Ot[w * 32 + ln][(r & 3) + 8 * (r >> 2) + 4 * h] = (_Float16)(o0[r] * inv);
    #pragma unroll
    for (int r = 0; r < 8; r++)
        Ot[w * 32 + ln][32 + (r & 3) + 8 * (r >> 2) + 4 * h] = (_Float16)(o1[r] * inv);
    __syncthreads();
    const int b = bh >> 3, hd = bh & 7;
    #pragma unroll
    for (int i = 0; i < 3; i++) {
        const int c2 = i * 256 + tid;
        const int row = c2 / 6, ch = c2 % 6;
        const int q = qt * 128 + row;
        *(f16x8*)&ab[(size_t)(b * 2048 + q) * 384 + hd * 48 + ch * 8] =
            *(const f16x8*)&Ot[row][ch * 8];
    }
}

// ---------------------------------------------------------------------------
// Proj GEMM: A = ab[8192][384] f16, Bt = wprojt[384][384] f16, +bias -> fp32
// 64x64 tile, BK=64, padded LDS, reg-prefetch.
// ---------------------------------------------------------------------------
__global__ __launch_bounds__(256) void proj_f16(const _Float16* __restrict__ A,
                                                const _Float16* __restrict__ Bt,
                                                const float* __restrict__ bias,
                                                float* __restrict__ out)
{
    __shared__ _Float16 As[64][72];
    __shared__ _Float16 Bs[64][72];
    const int tid = threadIdx.x;
    const int w = tid >> 6, lane = tid & 63, cl = lane & 15, quad = lane >> 4;
    const int bm = blockIdx.x, bn = blockIdx.y;

    f32x4 acc[4];
    const f32x4 z4 = {0.f, 0.f, 0.f, 0.f};
    #pragma unroll
    for (int t = 0; t < 4; t++) acc[t] = z4;

    const int ar = tid >> 3, ac = (tid & 7) * 8;
    const _Float16* Ag = A  + (size_t)(bm * 64 + ar) * 384 + ac;
    const _Float16* Bg = Bt + (size_t)(bn * 64 + ar) * 384 + ac;

    f16x8 pa[2], pb[2];
    #pragma unroll
    for (int j = 0; j < 2; j++) {
        pa[j] = *(const f16x8*)(Ag + (size_t)(32 * j) * 384);
        pb[j] = *(const f16x8*)(Bg + (size_t)(32 * j) * 384);
    }

    for (int k0 = 0; k0 < 384; k0 += 64) {
        __syncthreads();
        #pragma unroll
        for (int j = 0; j < 2; j++) {
            *(f16x8*)&As[ar + 32 * j][ac] = pa[j];
            *(f16x8*)&Bs[ar + 32 * j][ac] = pb[j];
        }
        __syncthreads();
        if (k0 + 64 < 384) {
            #pragma unroll
            for (int j = 0; j < 2; j++) {
                pa[j] = *(const f16x8*)(Ag + (size_t)(32 * j) * 384 + k0 + 64);
                pb[j] = *(const f16x8*)(Bg + (size_t)(32 * j) * 384 + k0 + 64);
            }
        }
        #pragma unroll
        for (int kh2 = 0; kh2 < 2; kh2++) {
            const f16x8 af = *(const f16x8*)&As[w * 16 + cl][kh2 * 32 + quad * 8];
            #pragma unroll
            for (int t = 0; t < 4; t++) {
                const f16x8 bf = *(const f16x8*)&Bs[t * 16 + cl][kh2 * 32 + quad * 8];
                acc[t] = __builtin_amdgcn_mfma_f32_16x16x32_f16(af, bf, acc[t], 0, 0, 0);
            }
        }
    }

    #pragma unroll
    for (int t = 0; t < 4; t++) {
        const int col = bn * 64 + t * 16 + cl;
        const float bv = bias[col];
        #pragma unroll
        for (int r = 0; r < 4; r++) {
            const int row = bm * 64 + w * 16 + quad * 4 + r;
            out[(size_t)row * 384 + col] = acc[t][r] + bv;
        }
    }
}

// ---------------------------------------------------------------------------
extern "C" void kernel_launch(void* const* d_in, const int* in_sizes, int n_in,
                              void* d_out, int out_size, void* d_ws, size_t ws_size,
                              hipStream_t stream) {
    const float* x     = (const float*)d_in[0];  // [4,2048,384]
    const float* Wqkv  = (const float*)d_in[1];  // [384,1152]
    const float* Wproj = (const float*)d_in[2];  // [384,384]
    const float* bproj = (const float*)d_in[3];  // [384]
    float* out = (float*)d_out;

    char* ws = (char*)d_ws;
    _Float16* xh     = (_Float16*)(ws + 0);          // 8192*384*2  = 6,291,456
    _Float16* wqkvt  = (_Float16*)(ws + 6291456);    // 1152*384*2  =   884,736
    _Float16* wprojt = (_Float16*)(ws + 7176192);    // 384*384*2   =   294,912
    _Float16* qh     = (_Float16*)(ws + 7471104);    // 32*2048*48*2 = 6,291,456
    _Float16* kh     = (_Float16*)(ws + 13762560);   // 6,291,456
    _Float16* vt     = (_Float16*)(ws + 20054016);   // 6,291,456
    _Float16* ab     = (_Float16*)(ws + 26345472);   // 6,291,456
    // total 32,636,928 B

    prep<<<400, 256, 0, stream>>>((const float4*)x, Wqkv, Wproj,
                                  (f16x4*)xh, wqkvt, wprojt);
    qkv_f16<<<dim3(64, 9), 256, 0, stream>>>(xh, wqkvt, qh, kh, vt);
    attn_f16<<<dim3(32, 16), 256, 0, stream>>>(qh, kh, vt, ab);
    proj_f16<<<dim3(128, 6), 256, 0, stream>>>(ab, wprojt, bproj, out);
}